// Round 1
// baseline (569.937 us; speedup 1.0000x reference)
//
#include <hip/hip_runtime.h>

// MON forward-backward splitting via Anderson acceleration, MI355X/gfx950.
// Fixed launch sequence (graph-capture safe), device-flag early exit.
// State (all in d_ws, ~160.3 MiB needed):
//   Fh[5]   f32  NHWC  83,886,080 B   (history of f-outputs; f32 so res can reach 1e-5)
//   G[5]    bf16 NHWC  41,943,040 B   (Fh - X history; feeds Gram only)
//   xnew    f32  NHWC  16,777,216 B
//   zm0/zm1 bf16 NHWC-swizzled 2x 8,388,608 B (conv input, channel-group XOR-swizzle by x&7)
//   xsw     bf16 NHWC-swizzled 8,388,608 B (mask-inject source)
//   Wb      bf16 [9][cout][cin-swz] 294,912 B
//   alpha/gram/gram-partials/res-partials/ctrl: small.

typedef unsigned short u16;
using short8 = __attribute__((ext_vector_type(8))) short;
using f32x4  = __attribute__((ext_vector_type(4))) float;

#define SLOT   4194304              // elements per history slot (32768 pixels * 128 ch)
#define LDSA   52224                // A tile: 6 rows * 34 cols * 256 B
#define LDSB   32768                // one W offset panel: 128*128 bf16
#define LDS_ROWMAX (LDSA + 2*LDSB)  // f32 [128][4]
#define LDS_ROWSUM (LDS_ROWMAX + 2048)
#define LDS_RED    (LDS_ROWSUM + 2048)
#define LDS_CONV   (LDS_RED + 64)   // = 121,920 B (static; 1 block/CU)

struct Ctrl { int done; int last_slot; float res; int pad; };

__device__ __forceinline__ u16 f2bf(float f) {
  unsigned u = __builtin_bit_cast(unsigned, f);
  unsigned r = (u + 0x7FFFu + ((u >> 16) & 1u)) >> 16;   // RNE, finite inputs
  return (u16)r;
}
__device__ __forceinline__ float bf2f(u16 h) {
  unsigned u = ((unsigned)h) << 16;
  return __builtin_bit_cast(float, u);
}
__device__ __forceinline__ void gl_lds16(const void* g, void* l) {
  __builtin_amdgcn_global_load_lds(
      (const __attribute__((address_space(1))) unsigned int*)g,
      (__attribute__((address_space(3))) unsigned int*)l, 16, 0, 0);
}

// ---------------- init ----------------
__global__ void k_init(float* gram, Ctrl* ctrl) {
  int t = threadIdx.x;
  if (t == 0) { ctrl->done = 0; ctrl->last_slot = 4; ctrl->res = 0.f; ctrl->pad = 0; }
  for (int i = t; i < 800; i += 64) gram[i] = 0.f;
}

// ---------------- weight pre-swizzle: W[cout][cin][ky][kx] -> Wb[o][cout][swz(cin)] bf16
__global__ void __launch_bounds__(256) k_prepw(const float* __restrict__ W, u16* __restrict__ Wb) {
  int t = blockIdx.x * 256 + threadIdx.x;       // exactly 9*128*128 threads
  int o = t >> 14;
  int rem = t & 16383;
  int cout = rem >> 7, cin = rem & 127;
  float v = W[(size_t)cout * 1152 + (size_t)cin * 9 + o];
  int g = cin >> 3;
  int pos = ((g ^ (cout & 7)) << 3) | (cin & 7);
  Wb[(size_t)o * 16384 + (size_t)cout * 128 + pos] = f2bf(v);
}

// ---------------- x NCHW f32 -> xsw (bf16 swizzled NHWC), and zm0 = mask ? x : 1/128
__global__ void __launch_bounds__(256) k_prepx(const float* __restrict__ x,
    const int* __restrict__ mask_, u16* __restrict__ xsw, u16* __restrict__ zm0) {
  int t = blockIdx.x * 256 + threadIdx.x;       // 524288 threads
  int g = t >> 15, p = t & 32767;
  int nb = p >> 10, gp = p & 1023, px = p & 31;
  int mk = mask_[p];
  const u16 ubf = 0x3C00;                       // bf16(1/128) exact
  short8 xv, zv;
#pragma unroll
  for (int u = 0; u < 8; ++u) {
    float v = x[(size_t)nb * 131072 + (size_t)(g * 8 + u) * 1024 + gp];
    u16 uv = f2bf(v);
    xv[u] = (short)uv;
    zv[u] = (short)(mk ? uv : ubf);
  }
  size_t off = (size_t)p * 128 + (size_t)((g ^ (px & 7)) << 3);
  *(short8*)(xsw + off) = xv;
  *(short8*)(zm0 + off) = zv;
}

// ---------------- conv + softmax eval:  fnew = softmax_ch(0.1*z + 0.9*(conv(zm)+b))
// also writes G[slot] = fnew - z, res partials, optionally zm_next from fnew.
__global__ void __launch_bounds__(512) k_conv(
    const u16* __restrict__ zm, const float* __restrict__ z_in, float z_const,
    const u16* __restrict__ Wb, const float* __restrict__ bias,
    float* __restrict__ Fh_out, u16* __restrict__ G_out,
    float* __restrict__ res_part, int write_zm_next, u16* __restrict__ zm_next,
    const u16* __restrict__ xsw, const int* __restrict__ mask_,
    const Ctrl* __restrict__ ctrl, int gated)
{
  if (gated && ctrl->done) return;
  __shared__ char smem[LDS_CONV];
  char* As = smem;
  char* Bs = smem + LDSA;
  float* rowmax_s = (float*)(smem + LDS_ROWMAX);
  float* rowsum_s = (float*)(smem + LDS_ROWSUM);
  float* red      = (float*)(smem + LDS_RED);

  const int tid = threadIdx.x;
  const int wid = tid >> 6, lane = tid & 63;
  const int lhi = lane >> 4, llo = lane & 15;
  const int wr = wid >> 2, wc = wid & 3;          // wave tile: 64 rows x 32 cols
  const int bid = blockIdx.x;                      // 256 blocks: (n, 4-row tile)
  const int n = bid >> 3, yt = bid & 7, y0 = yt << 2;
  const int pixbase = (n << 10) + (y0 << 5);
  const int woff = (tid & ~63) << 4;               // wave-uniform LDS chunk base

  // ---- stage A (6 halo'd rows, zero pads), B offset 0 ----
  {
#pragma unroll
    for (int r = 0; r < 6; ++r) {
      int y = y0 - 1 + r;
      char* ldsrow = As + r * 8704 + 256;          // cols 1..32
      if ((unsigned)y < 32u) {
        const char* src = (const char*)zm + (size_t)(n * 1024 + y * 32) * 256;
        gl_lds16(src + tid * 16, ldsrow + woff);
      } else {
        f32x4 zz = {0.f, 0.f, 0.f, 0.f};
        *(f32x4*)(ldsrow + tid * 16) = zz;
      }
    }
    if (tid < 192) {                               // pad cols 0 and 33, all 6 rows
      int r = tid >> 5, cc = tid & 31;
      int col = (cc < 16) ? 0 : 33, g = cc & 15;
      f32x4 zz = {0.f, 0.f, 0.f, 0.f};
      *(f32x4*)(As + r * 8704 + col * 256 + g * 16) = zz;
    }
    const char* wsrc = (const char*)Wb;
#pragma unroll
    for (int i = 0; i < 4; ++i)
      gl_lds16(wsrc + i * 8192 + tid * 16, Bs + i * 8192 + woff);
  }
  __syncthreads();

  f32x4 acc[4][2] = {};
  for (int o = 0; o < 9; ++o) {
    if (o < 8) {                                   // prefetch next W panel
      const char* wsrc = (const char*)Wb + (size_t)(o + 1) * 32768;
      char* dst = Bs + ((o + 1) & 1) * LDSB;
#pragma unroll
      for (int i = 0; i < 4; ++i)
        gl_lds16(wsrc + i * 8192 + tid * 16, dst + i * 8192 + woff);
    }
    const int dy = o / 3;
    const int dx = o - dy * 3;
    const char* Bbuf = Bs + (o & 1) * LDSB;
#pragma unroll
    for (int kk = 0; kk < 4; ++kk) {
      int kg = (kk << 2) + lhi;                    // k-group within offset (0..15)
      short8 af[4];
#pragma unroll
      for (int m2 = 0; m2 < 4; ++m2) {
        int p = (wr << 6) + (m2 << 4) + llo;       // A-row = pixel (lane&15)
        int py = p >> 5, px = p & 31;
        int r = py + dy, cl = px + dx;
        int sg = kg ^ ((cl - 1) & 7);
        af[m2] = *(const short8*)(As + r * 8704 + (cl << 8) + (sg << 4));
      }
      short8 bfr[2];
#pragma unroll
      for (int nf = 0; nf < 2; ++nf) {
        int colc = (wc << 5) + (nf << 4) + llo;    // B^T-row = out_ch (lane&15)
        int sg = kg ^ (colc & 7);
        bfr[nf] = *(const short8*)(Bbuf + (colc << 8) + (sg << 4));
      }
#pragma unroll
      for (int m2 = 0; m2 < 4; ++m2)
#pragma unroll
        for (int nf = 0; nf < 2; ++nf)
          acc[m2][nf] = __builtin_amdgcn_mfma_f32_16x16x32_bf16(af[m2], bfr[nf], acc[m2][nf], 0, 0, 0);
    }
    __syncthreads();
  }

  // ---- epilogue: pre = 0.1 z + 0.9 (acc+b); softmax over 128 cols per pixel-row ----
  float zreg[4][2][4];
  const int colbase = wc << 5;
  float b0 = bias[colbase + llo];
  float b1 = bias[colbase + 16 + llo];
#pragma unroll
  for (int m2 = 0; m2 < 4; ++m2)
#pragma unroll
    for (int rr = 0; rr < 4; ++rr) {
      const int row = (wr << 6) + (m2 << 4) + (lhi << 2) + rr;   // C/D: col=lane&15, row=(lane>>4)*4+reg
      const size_t rbase = (size_t)(pixbase + row) * 128;
#pragma unroll
      for (int nf = 0; nf < 2; ++nf) {
        const int col = colbase + (nf << 4) + llo;
        float z = z_in ? z_in[rbase + col] : z_const;
        zreg[m2][nf][rr] = z;
        acc[m2][nf][rr] = 0.1f * z + 0.9f * (acc[m2][nf][rr] + (nf ? b1 : b0));
      }
    }
  // row max (32 cols in-wave via shfl over the 16-lane group, then 4 waves via LDS)
#pragma unroll
  for (int m2 = 0; m2 < 4; ++m2)
#pragma unroll
    for (int rr = 0; rr < 4; ++rr) {
      float v = fmaxf(acc[m2][0][rr], acc[m2][1][rr]);
      v = fmaxf(v, __shfl_xor(v, 1)); v = fmaxf(v, __shfl_xor(v, 2));
      v = fmaxf(v, __shfl_xor(v, 4)); v = fmaxf(v, __shfl_xor(v, 8));
      const int row = (wr << 6) + (m2 << 4) + (lhi << 2) + rr;
      if (llo == 0) rowmax_s[(row << 2) + wc] = v;
    }
  __syncthreads();
#pragma unroll
  for (int m2 = 0; m2 < 4; ++m2)
#pragma unroll
    for (int rr = 0; rr < 4; ++rr) {
      const int row = (wr << 6) + (m2 << 4) + (lhi << 2) + rr;
      float M = fmaxf(fmaxf(rowmax_s[row << 2], rowmax_s[(row << 2) + 1]),
                      fmaxf(rowmax_s[(row << 2) + 2], rowmax_s[(row << 2) + 3]));
      float e0 = __expf(acc[m2][0][rr] - M);
      float e1 = __expf(acc[m2][1][rr] - M);
      acc[m2][0][rr] = e0; acc[m2][1][rr] = e1;
      float s = e0 + e1;
      s += __shfl_xor(s, 1); s += __shfl_xor(s, 2);
      s += __shfl_xor(s, 4); s += __shfl_xor(s, 8);
      if (llo == 0) rowsum_s[(row << 2) + wc] = s;
    }
  __syncthreads();

  float sd = 0.f, sf = 0.f;
#pragma unroll
  for (int m2 = 0; m2 < 4; ++m2)
#pragma unroll
    for (int rr = 0; rr < 4; ++rr) {
      const int row = (wr << 6) + (m2 << 4) + (lhi << 2) + rr;
      const int gp = pixbase + row;
      const size_t rbase = (size_t)gp * 128;
      float S = rowsum_s[row << 2] + rowsum_s[(row << 2) + 1]
              + rowsum_s[(row << 2) + 2] + rowsum_s[(row << 2) + 3];
      float invS = 1.0f / S;
      const int px = gp & 31;
      const int mk = write_zm_next ? mask_[gp] : 0;
#pragma unroll
      for (int nf = 0; nf < 2; ++nf) {
        const int col = colbase + (nf << 4) + llo;
        float fnew = acc[m2][nf][rr] * invS;
        Fh_out[rbase + col] = fnew;
        float gd = fnew - zreg[m2][nf][rr];
        G_out[rbase + col] = f2bf(gd);
        sd += gd * gd; sf += fnew * fnew;
        if (write_zm_next) {
          const int gg = col >> 3;
          const size_t zoff = rbase + (size_t)(((gg ^ (px & 7)) << 3) | (col & 7));
          zm_next[zoff] = mk ? xsw[zoff] : f2bf(fnew);
        }
      }
    }
#pragma unroll
  for (int off = 1; off < 64; off <<= 1) { sd += __shfl_xor(sd, off); sf += __shfl_xor(sf, off); }
  if (lane == 0) { red[(wid << 1)] = sd; red[(wid << 1) + 1] = sf; }
  __syncthreads();
  if (tid == 0) {
    float a = 0.f, b = 0.f;
#pragma unroll
    for (int i = 0; i < 8; ++i) { a += red[i * 2]; b += red[i * 2 + 1]; }
    res_part[(bid << 1)] = a; res_part[(bid << 1) + 1] = b;
  }
}

// ---------------- xnew = sum_j alpha_j * Fh_j ; zm = mask ? x : bf16(xnew)
__global__ void __launch_bounds__(256) k_xnew(
    const float* __restrict__ Fh, const float* __restrict__ alpha,
    float* __restrict__ xnew, u16* __restrict__ zm,
    const u16* __restrict__ xsw, const int* __restrict__ mask_,
    const Ctrl* __restrict__ ctrl)
{
  if (ctrl->done) return;
  int t = blockIdx.x * 256 + threadIdx.x;       // 524288 threads
  int p = t >> 4, g = t & 15;
  int nb = p >> 10, px = p & 31;
  const float* al = alpha + nb * 5;
  float a0 = al[0], a1 = al[1], a2 = al[2], a3 = al[3], a4 = al[4];
  size_t base = (size_t)p * 128 + (size_t)(g << 3);
  f32x4 va, vb;
  {
    const float* f = Fh + base;
    f32x4 x0a = *(const f32x4*)(f);               f32x4 x0b = *(const f32x4*)(f + 4);
    f32x4 x1a = *(const f32x4*)(f + SLOT);        f32x4 x1b = *(const f32x4*)(f + SLOT + 4);
    f32x4 x2a = *(const f32x4*)(f + 2 * SLOT);    f32x4 x2b = *(const f32x4*)(f + 2 * SLOT + 4);
    f32x4 x3a = *(const f32x4*)(f + 3 * SLOT);    f32x4 x3b = *(const f32x4*)(f + 3 * SLOT + 4);
    f32x4 x4a = *(const f32x4*)(f + 4 * SLOT);    f32x4 x4b = *(const f32x4*)(f + 4 * SLOT + 4);
    va = a0 * x0a + a1 * x1a + a2 * x2a + a3 * x3a + a4 * x4a;
    vb = a0 * x0b + a1 * x1b + a2 * x2b + a3 * x3b + a4 * x4b;
  }
  *(f32x4*)(xnew + base) = va;
  *(f32x4*)(xnew + base + 4) = vb;
  int mk = mask_[p];
  size_t zoff = (size_t)p * 128 + (size_t)((g ^ (px & 7)) << 3);
  if (mk) {
    *(short8*)(zm + zoff) = *(const short8*)(xsw + zoff);
  } else {
    short8 o;
#pragma unroll
    for (int u = 0; u < 4; ++u) o[u] = (short)f2bf(va[u]);
#pragma unroll
    for (int u = 0; u < 4; ++u) o[4 + u] = (short)f2bf(vb[u]);
    *(short8*)(zm + zoff) = o;
  }
}

// ---------------- gram partial dots: <G[slot], G[j]> per (batch, chunk)
__global__ void __launch_bounds__(256) k_gram(
    const u16* __restrict__ G, float* __restrict__ gpart, int slot,
    const Ctrl* __restrict__ ctrl, int gated)
{
  if (gated && ctrl->done) return;
  int bid = blockIdx.x;                          // 512 = 32 batches * 16 chunks
  int b = bid >> 4, ch = bid & 15;
  size_t base = (size_t)b * 131072 + (size_t)ch * 8192;
  const u16* gs = G + (size_t)slot * SLOT + base;
  float acc[5] = {0.f, 0.f, 0.f, 0.f, 0.f};
  for (int i0 = threadIdx.x * 8; i0 < 8192; i0 += 2048) {
    short8 sv = *(const short8*)(gs + i0);
    float s[8];
#pragma unroll
    for (int u = 0; u < 8; ++u) s[u] = bf2f((u16)sv[u]);
#pragma unroll
    for (int j = 0; j < 5; ++j) {
      short8 gv = *(const short8*)(G + (size_t)j * SLOT + base + i0);
      float a = 0.f;
#pragma unroll
      for (int u = 0; u < 8; ++u) a += s[u] * bf2f((u16)gv[u]);
      acc[j] += a;
    }
  }
  int lane = threadIdx.x & 63, w = threadIdx.x >> 6;
  __shared__ float red[4][5];
#pragma unroll
  for (int j = 0; j < 5; ++j) {
    float v = acc[j];
#pragma unroll
    for (int off = 1; off < 64; off <<= 1) v += __shfl_xor(v, off);
    if (lane == 0) red[w][j] = v;
  }
  __syncthreads();
  if (threadIdx.x == 0) {
#pragma unroll
    for (int j = 0; j < 5; ++j)
      gpart[(size_t)((b << 4) + ch) * 5 + j] = red[0][j] + red[1][j] + red[2][j] + red[3][j];
  }
}

// ---------------- residual check + gram reduce + bordered 6x6 solve (per batch)
__global__ void k_solve(float* gram, const float* gpa, int sa,
                        const float* gpb, int sb,
                        const float* res_part, int check_res, int last_slot_if_done,
                        int kk, float* alpha, Ctrl* ctrl)
{
  __shared__ float rbuf[128];
  __shared__ int flag;
  __shared__ double S[32][6][7];
  int t = threadIdx.x;                           // 192 threads
  if (ctrl->done) return;
  if (t == 0) flag = 0;
  __syncthreads();
  if (check_res) {
    if (t < 64) {
      float sd = 0.f, sf = 0.f;
      for (int i = t; i < 256; i += 64) { sd += res_part[i * 2]; sf += res_part[i * 2 + 1]; }
      rbuf[t] = sd; rbuf[64 + t] = sf;
    }
    __syncthreads();
    if (t == 0) {
      float a = 0.f, b = 0.f;
      for (int i = 0; i < 64; ++i) { a += rbuf[i]; b += rbuf[64 + i]; }
      float res = sqrtf(a) / (1e-5f + sqrtf(b));
      ctrl->res = res;
      if (res < 1e-5f) { ctrl->done = 1; ctrl->last_slot = last_slot_if_done; flag = 1; }
    }
    __syncthreads();
    if (flag) return;
  }
  if (t < 160) {                                 // reduce slot sa row/col
    int b = t / 5, j = t % 5;
    float s = 0.f;
    for (int ch = 0; ch < 16; ++ch) s += gpa[(size_t)((b << 4) + ch) * 5 + j];
    gram[b * 25 + sa * 5 + j] = s;
    gram[b * 25 + j * 5 + sa] = s;
  }
  __syncthreads();
  if (sb >= 0 && t < 160) {                      // k=2 only: also slot 1 (order matters)
    int b = t / 5, j = t % 5;
    float s = 0.f;
    for (int ch = 0; ch < 16; ++ch) s += gpb[(size_t)((b << 4) + ch) * 5 + j];
    gram[b * 25 + sb * 5 + j] = s;
    gram[b * 25 + j * 5 + sb] = s;
  }
  __syncthreads();
  if (t < 32) {
    int b = t;
    int nact = kk < 5 ? kk : 5;
    double (*A)[7] = S[b];
    for (int i = 0; i < 5; ++i)
      for (int j = 0; j < 5; ++j) {
        double v;
        if (i < nact && j < nact)
          v = (double)gram[b * 25 + i * 5 + j] + ((i == j) ? 1e-4 : 0.0);
        else
          v = (i == j) ? 1.0 : 0.0;
        A[i + 1][j + 1] = v;
      }
    A[0][0] = 0.0;
    for (int j = 0; j < 5; ++j) { double aj = (j < nact) ? 1.0 : 0.0; A[0][j + 1] = aj; A[j + 1][0] = aj; }
    A[0][6] = 1.0;
    for (int i = 1; i < 6; ++i) A[i][6] = 0.0;
    for (int c = 0; c < 6; ++c) {                // partial-pivot Gaussian elimination
      int p = c; double mx = fabs(A[c][c]);
      for (int r = c + 1; r < 6; ++r) { double v = fabs(A[r][c]); if (v > mx) { mx = v; p = r; } }
      if (p != c) for (int q = c; q < 7; ++q) { double tmp = A[c][q]; A[c][q] = A[p][q]; A[p][q] = tmp; }
      double piv = A[c][c];
      for (int r = c + 1; r < 6; ++r) {
        double f = A[r][c] / piv;
        for (int q = c; q < 7; ++q) A[r][q] -= f * A[c][q];
      }
    }
    double sol[6];
    for (int r = 5; r >= 0; --r) {
      double s = A[r][6];
      for (int q = r + 1; q < 6; ++q) s -= A[r][q] * sol[q];
      sol[r] = s / A[r][r];
    }
    for (int j = 0; j < 5; ++j) alpha[b * 5 + j] = (float)sol[j + 1];
  }
}

// ---------------- final: Fh[last_slot] NHWC f32 -> d_out NCHW f32
__global__ void __launch_bounds__(256) k_out(const float* __restrict__ Fh,
    const Ctrl* __restrict__ ctrl, float* __restrict__ out)
{
  __shared__ float T[64][129];
  int slot = ctrl->last_slot;
  const float* src = Fh + (size_t)slot * SLOT;
  int bid = blockIdx.x;                          // 512 = 32 batches * 16 segments
  int nb = bid >> 4, seg = bid & 15;
  int pixbase = (nb << 10) + (seg << 6);
  for (int it = 0; it < 32; ++it) {
    int idx = it * 256 + threadIdx.x;
    int pix = idx >> 7, c = idx & 127;
    T[pix][c] = src[(size_t)(pixbase + pix) * 128 + c];
  }
  __syncthreads();
  for (int it = 0; it < 32; ++it) {
    int idx = it * 256 + threadIdx.x;
    int c = idx >> 6, pix = idx & 63;
    out[(size_t)((nb << 7) + c) * 1024 + (seg << 6) + pix] = T[pix][c];
  }
}

extern "C" void kernel_launch(void* const* d_in, const int* in_sizes, int n_in,
                              void* d_out, int out_size, void* d_ws, size_t ws_size,
                              hipStream_t stream) {
  const float* x    = (const float*)d_in[0];   // [32,128,32,32]
  const float* W    = (const float*)d_in[1];   // [128,128,3,3]
  const float* bias = (const float*)d_in[2];   // [128]
  const int*   mask = (const int*)d_in[3];     // [32,1,32,32]
  float* out = (float*)d_out;
  char* ws = (char*)d_ws;

  float* Fh    = (float*)(ws + 0);
  u16*   G     = (u16*)(ws + 83886080);
  float* xnew  = (float*)(ws + 125829120);
  u16*   zm0   = (u16*)(ws + 142606336);
  u16*   zm1   = (u16*)(ws + 150994944);
  u16*   xsw   = (u16*)(ws + 159383552);
  u16*   Wb    = (u16*)(ws + 167772160);
  float* alpha = (float*)(ws + 168067072);
  float* gram  = (float*)(ws + 168067712);
  float* gp0   = (float*)(ws + 168070912);
  float* gp1   = (float*)(ws + 168081152);
  float* resp  = (float*)(ws + 168091392);
  Ctrl*  ctrl  = (Ctrl*)(ws + 168093440);

  k_init<<<1, 64, 0, stream>>>(gram, ctrl);
  hipMemsetAsync(G, 0, (size_t)5 * SLOT * 2, stream);
  k_prepw<<<576, 256, 0, stream>>>(W, Wb);
  k_prepx<<<2048, 256, 0, stream>>>(x, mask, xsw, zm0);

  // F0 = f(z0), z0 = 1/128 uniform; also emit zm for eval1 directly from F0.
  k_conv<<<256, 512, 0, stream>>>(zm0, nullptr, 1.0f / 128.0f, Wb, bias,
        Fh, G, resp, 1, zm1, xsw, mask, ctrl, 0);
  k_gram<<<512, 256, 0, stream>>>(G, gp0, 0, ctrl, 0);
  // F1 = f(F0)
  k_conv<<<256, 512, 0, stream>>>(zm1, Fh, 0.f, Wb, bias,
        Fh + SLOT, G + SLOT, resp, 0, nullptr, xsw, mask, ctrl, 0);
  k_gram<<<512, 256, 0, stream>>>(G, gp1, 1, ctrl, 0);

  for (int k = 2; k < 50; ++k) {
    int slot = k % 5;
    if (k == 2)
      k_solve<<<1, 192, 0, stream>>>(gram, gp0, 0, gp1, 1, resp, 0, 0, k, alpha, ctrl);
    else
      k_solve<<<1, 192, 0, stream>>>(gram, ((k - 1) & 1) ? gp1 : gp0, (k - 1) % 5,
                                     nullptr, -1, resp, 1, (k - 1) % 5, k, alpha, ctrl);
    k_xnew<<<2048, 256, 0, stream>>>(Fh, alpha, xnew, zm0, xsw, mask, ctrl);
    k_conv<<<256, 512, 0, stream>>>(zm0, xnew, 0.f, Wb, bias,
          Fh + (size_t)slot * SLOT, G + (size_t)slot * SLOT, resp, 0, nullptr, xsw, mask, ctrl, 1);
    k_gram<<<512, 256, 0, stream>>>(G, (k & 1) ? gp1 : gp0, slot, ctrl, 1);
  }
  k_out<<<512, 256, 0, stream>>>(Fh, ctrl, out);
  (void)in_sizes; (void)n_in; (void)out_size; (void)ws_size;
}

// Round 2
// 556.528 us; speedup vs baseline: 1.0241x; 1.0241x over previous
//
#include <hip/hip_runtime.h>

// MON forward-backward splitting via Anderson acceleration, MI355X/gfx950.
// R1: conv restructured (2-row tiles, 512 blocks, no B-LDS, 1 barrier, 2 blocks/CU),
//     gram fused into conv epilogue (packed-linear G layout),
//     solve+res fused into k_fx head. 2 dispatches per iteration.

typedef unsigned short u16;
using short8 = __attribute__((ext_vector_type(8))) short;
using f32x4  = __attribute__((ext_vector_type(4))) float;

#define SLOT 4194304              // elements per history slot (32768 px * 128 ch)

struct Ctrl { int done; int last_slot; float res; int pad; };

__device__ __forceinline__ u16 f2bf(float f) {
  unsigned u = __builtin_bit_cast(unsigned, f);
  unsigned r = (u + 0x7FFFu + ((u >> 16) & 1u)) >> 16;   // RNE, finite inputs
  return (u16)r;
}
__device__ __forceinline__ float bf2f(u16 h) {
  unsigned u = ((unsigned)h) << 16;
  return __builtin_bit_cast(float, u);
}
__device__ __forceinline__ void gl_lds16(const void* g, void* l) {
  __builtin_amdgcn_global_load_lds(
      (const __attribute__((address_space(1))) unsigned int*)g,
      (__attribute__((address_space(3))) unsigned int*)l, 16, 0, 0);
}

// ---------------- init ----------------
__global__ void k_init(float* gram, Ctrl* ctrl) {
  int t = threadIdx.x;
  if (t == 0) { ctrl->done = 0; ctrl->last_slot = 4; ctrl->res = 0.f; ctrl->pad = 0; }
  for (int i = t; i < 800; i += 64) gram[i] = 0.f;
}

// ---------------- W[cout][cin][ky][kx] f32 -> Wb[o][cout][cin] bf16 (plain; global B loads)
__global__ void __launch_bounds__(256) k_prepw(const float* __restrict__ W, u16* __restrict__ Wb) {
  int t = blockIdx.x * 256 + threadIdx.x;       // 9*128*128 threads
  int o = t >> 14;
  int rem = t & 16383;
  int cout = rem >> 7, cin = rem & 127;
  float v = W[(size_t)cout * 1152 + (size_t)cin * 9 + o];
  Wb[(size_t)o * 16384 + (size_t)cout * 128 + cin] = f2bf(v);
}

// ---------------- x NCHW f32 -> xsw (bf16 swizzled NHWC), zm0 = mask ? x : 1/128
__global__ void __launch_bounds__(256) k_prepx(const float* __restrict__ x,
    const int* __restrict__ mask_, u16* __restrict__ xsw, u16* __restrict__ zm0) {
  int t = blockIdx.x * 256 + threadIdx.x;       // 524288 threads
  int g = t >> 15, p = t & 32767;
  int nb = p >> 10, gp = p & 1023, px = p & 31;
  int mk = mask_[p];
  const u16 ubf = 0x3C00;                       // bf16(1/128) exact
  short8 xv, zv;
#pragma unroll
  for (int u = 0; u < 8; ++u) {
    float v = x[(size_t)nb * 131072 + (size_t)(g * 8 + u) * 1024 + gp];
    u16 uv = f2bf(v);
    xv[u] = (short)uv;
    zv[u] = (short)(mk ? uv : ubf);
  }
  size_t off = (size_t)p * 128 + (size_t)((g ^ (px & 7)) << 3);
  *(short8*)(xsw + off) = xv;
  *(short8*)(zm0 + off) = zv;
}

// ---------------- fused conv+softmax+G+gram+res-partials
// 512 blocks (n = bid>>4, 2-row tile yt = bid&15), 512 threads, 8 waves.
// Wave = 64 px x 16 ch; B fragments straight from global Wb (L2-hot).
__global__ void __launch_bounds__(512, 4) k_conv(
    const u16* __restrict__ zm, const float* __restrict__ z_in, float z_const,
    const u16* __restrict__ Wb, const float* __restrict__ bias,
    float* __restrict__ Fh_out, u16* __restrict__ G_all, int slot,
    float* __restrict__ gpart, float* __restrict__ res_part,
    const Ctrl* __restrict__ ctrl, int gated)
{
  if (gated && ctrl->done) return;
  __shared__ char smem[39424];
  char*  As       = smem;                        // 4 rows * 34 cols * 256B = 34816
  float* rowmax_s = (float*)(smem + 34816);      // 64 rows * 8 waves
  float* rowsum_s = (float*)(smem + 36864);
  float* red      = (float*)(smem + 38912);      // 8 waves * 8

  const int tid = threadIdx.x;
  const int wid = tid >> 6, lane = tid & 63;
  const int lhi = lane >> 4, llo = lane & 15;
  const int bid = blockIdx.x;
  const int n = bid >> 4, yt = bid & 15, y0 = yt << 1;
  const int pixbase = (n << 10) + (y0 << 5);
  const int woff = (tid & ~63) << 4;

  // ---- stage 4 halo'd rows of zm into LDS (pre-swizzled global -> linear LDS) ----
#pragma unroll
  for (int r = 0; r < 4; ++r) {
    int y = y0 - 1 + r;
    char* ldsrow = As + r * 8704 + 256;          // cols 1..32
    if ((unsigned)y < 32u) {
      const char* src = (const char*)zm + (size_t)((n << 10) + (y << 5)) * 256;
      gl_lds16(src + tid * 16, ldsrow + woff);
    } else {
      f32x4 zz = {0.f, 0.f, 0.f, 0.f};
      *(f32x4*)(ldsrow + tid * 16) = zz;
    }
  }
  if (tid < 128) {                               // zero pads: cols 0 and 33, 4 rows
    int r = tid >> 5, cc = tid & 31;
    int col = (cc < 16) ? 0 : 33, gc = cc & 15;
    f32x4 zz = {0.f, 0.f, 0.f, 0.f};
    *(f32x4*)(As + r * 8704 + col * 256 + gc * 16) = zz;
  }

  const int colc = (wid << 4) + llo;             // this wave's 16 out-channels
  short8 bf[2][4];
#pragma unroll
  for (int kk = 0; kk < 4; ++kk) {               // preload offset-0 B fragments
    int kg = (kk << 2) + lhi;
    bf[0][kk] = *(const short8*)(Wb + colc * 128 + kg * 8);
  }
  __syncthreads();

  f32x4 acc[4] = {{0,0,0,0},{0,0,0,0},{0,0,0,0},{0,0,0,0}};
#pragma unroll
  for (int o = 0; o < 9; ++o) {
    if (o < 8) {                                 // prefetch next offset's B frags
#pragma unroll
      for (int kk = 0; kk < 4; ++kk) {
        int kg = (kk << 2) + lhi;
        bf[(o + 1) & 1][kk] = *(const short8*)(Wb + (o + 1) * 16384 + colc * 128 + kg * 8);
      }
    }
    const int dy = o / 3, dx = o % 3;
#pragma unroll
    for (int kk = 0; kk < 4; ++kk) {
      const int kg = (kk << 2) + lhi;
      short8 af[4];
#pragma unroll
      for (int m2 = 0; m2 < 4; ++m2) {
        int p = (m2 << 4) + llo;                 // A-row = pixel
        int r = (p >> 5) + dy, cl = (p & 31) + dx;
        int sg = kg ^ ((cl - 1) & 7);
        af[m2] = *(const short8*)(As + r * 8704 + (cl << 8) + (sg << 4));
      }
#pragma unroll
      for (int m2 = 0; m2 < 4; ++m2)
        acc[m2] = __builtin_amdgcn_mfma_f32_16x16x32_bf16(af[m2], bf[o & 1][kk], acc[m2], 0, 0, 0);
    }
  }

  // ---- epilogue: pre = 0.1 z + 0.9 (acc+b); softmax over 128 ch per pixel ----
  float zreg[16];
  float bc = bias[colc];
#pragma unroll
  for (int m2 = 0; m2 < 4; ++m2)
#pragma unroll
    for (int rr = 0; rr < 4; ++rr) {
      int pixel = (m2 << 4) + (lhi << 2) + rr;   // C/D: col=lane&15, row=(lane>>4)*4+reg
      float z = z_in ? z_in[(size_t)(pixbase + pixel) * 128 + colc] : z_const;
      zreg[m2 * 4 + rr] = z;
      acc[m2][rr] = 0.1f * z + 0.9f * (acc[m2][rr] + bc);
    }
#pragma unroll
  for (int m2 = 0; m2 < 4; ++m2)
#pragma unroll
    for (int rr = 0; rr < 4; ++rr) {             // in-wave 16-ch max
      float v = acc[m2][rr];
      v = fmaxf(v, __shfl_xor(v, 1)); v = fmaxf(v, __shfl_xor(v, 2));
      v = fmaxf(v, __shfl_xor(v, 4)); v = fmaxf(v, __shfl_xor(v, 8));
      if (llo == 0) rowmax_s[((m2 << 4) + (lhi << 2) + rr) * 8 + wid] = v;
    }
  __syncthreads();
#pragma unroll
  for (int m2 = 0; m2 < 4; ++m2)
#pragma unroll
    for (int rr = 0; rr < 4; ++rr) {
      int pixel = (m2 << 4) + (lhi << 2) + rr;
      f32x4 m0 = *(const f32x4*)&rowmax_s[pixel * 8];
      f32x4 m1 = *(const f32x4*)&rowmax_s[pixel * 8 + 4];
      float M = fmaxf(fmaxf(fmaxf(m0[0], m0[1]), fmaxf(m0[2], m0[3])),
                      fmaxf(fmaxf(m1[0], m1[1]), fmaxf(m1[2], m1[3])));
      float e = __expf(acc[m2][rr] - M);
      acc[m2][rr] = e;
      float s = e;
      s += __shfl_xor(s, 1); s += __shfl_xor(s, 2);
      s += __shfl_xor(s, 4); s += __shfl_xor(s, 8);
      if (llo == 0) rowsum_s[pixel * 8 + wid] = s;
    }
  __syncthreads();

  float sd = 0.f, sf = 0.f;
  float gd16[16];
#pragma unroll
  for (int m2 = 0; m2 < 4; ++m2)
#pragma unroll
    for (int rr = 0; rr < 4; ++rr) {
      int pixel = (m2 << 4) + (lhi << 2) + rr;
      f32x4 s0 = *(const f32x4*)&rowsum_s[pixel * 8];
      f32x4 s1 = *(const f32x4*)&rowsum_s[pixel * 8 + 4];
      float S = s0[0] + s0[1] + s0[2] + s0[3] + s1[0] + s1[1] + s1[2] + s1[3];
      float fnew = acc[m2][rr] * (1.0f / S);
      Fh_out[(size_t)(pixbase + pixel) * 128 + colc] = fnew;
      float gd = fnew - zreg[m2 * 4 + rr];
      gd16[m2 * 4 + rr] = gd;
      sd += gd * gd; sf += fnew * fnew;
    }
  // packed-linear G store (coalesced 2x16B per thread)
  {
    short8 g0, g1;
#pragma unroll
    for (int i = 0; i < 8; ++i) { g0[i] = (short)f2bf(gd16[i]); g1[i] = (short)f2bf(gd16[8 + i]); }
    size_t gb = ((size_t)bid * 512 + tid) * 16;
    u16* Gs = G_all + (size_t)slot * SLOT;
    *(short8*)(Gs + gb) = g0;
    *(short8*)(Gs + gb + 8) = g1;
    // gram partials vs all 5 slots (own slot from registers)
    float gacc[5];
#pragma unroll
    for (int j = 0; j < 5; ++j) {
      if (j == slot) {
        float a = 0.f;
#pragma unroll
        for (int i = 0; i < 16; ++i) a += gd16[i] * gd16[i];
        gacc[j] = a;
      } else {
        short8 h0 = *(const short8*)(G_all + (size_t)j * SLOT + gb);
        short8 h1 = *(const short8*)(G_all + (size_t)j * SLOT + gb + 8);
        float a = 0.f;
#pragma unroll
        for (int i = 0; i < 8; ++i) a += gd16[i] * bf2f((u16)h0[i]) + gd16[8 + i] * bf2f((u16)h1[i]);
        gacc[j] = a;
      }
    }
    float vals[7] = {gacc[0], gacc[1], gacc[2], gacc[3], gacc[4], sd, sf};
#pragma unroll
    for (int i = 0; i < 7; ++i) {
      float v = vals[i];
#pragma unroll
      for (int off = 1; off < 64; off <<= 1) v += __shfl_xor(v, off);
      if (lane == 0) red[wid * 8 + i] = v;
    }
    __syncthreads();
    if (tid < 7) {
      float s = 0.f;
#pragma unroll
      for (int w = 0; w < 8; ++w) s += red[w * 8 + tid];
      if (tid < 5)       gpart[(size_t)bid * 5 + tid] = s;
      else if (tid == 5) res_part[bid * 2] = s;
      else               res_part[bid * 2 + 1] = s;
    }
  }
}

// ---------------- fused res-check + gram update + 6x6 solve + xnew + zm
// 1024 blocks (n = bid>>5, 32 px per block), 512 threads.
__global__ void __launch_bounds__(512) k_fx(
    const float* __restrict__ Fh, float* __restrict__ xnew, u16* __restrict__ zm,
    const u16* __restrict__ xsw, const int* __restrict__ mask_,
    const float* __restrict__ gpa, int sa, const float* __restrict__ gpb, int sb,
    const float* __restrict__ resp, int check_res, int last_slot_if_done,
    int kk_iter, int mode1, float* __restrict__ gram, Ctrl* __restrict__ ctrl)
{
  if (ctrl->done) return;
  __shared__ float alpha_s[5];
  __shared__ int flag;
  int t = threadIdx.x, bid = blockIdx.x, n = bid >> 5;
  if (t == 0) flag = 0;
  __syncthreads();
  if (!mode1) {
    if (check_res && t < 64) {
      float sd = 0.f, sf = 0.f;
      for (int i = t; i < 512; i += 64) { sd += resp[2 * i]; sf += resp[2 * i + 1]; }
#pragma unroll
      for (int off = 1; off < 64; off <<= 1) { sd += __shfl_xor(sd, off); sf += __shfl_xor(sf, off); }
      if (t == 0) {
        float res = sqrtf(sd) / (1e-5f + sqrtf(sf));
        if (res < 1e-5f) { flag = 1; ctrl->done = 1; ctrl->last_slot = last_slot_if_done; }
      }
    }
    __syncthreads();
    if (flag) return;
    if (t < 5) {                                 // fold new gram row/col (slot sa)
      float s = 0.f;
      for (int c = 0; c < 16; ++c) s += gpa[(size_t)((n << 4) + c) * 5 + t];
      gram[n * 25 + sa * 5 + t] = s;
      gram[n * 25 + t * 5 + sa] = s;
    }
    __syncthreads();
    if (sb >= 0 && t < 5) {                      // k=2 only: slot sb after sa
      float s = 0.f;
      for (int c = 0; c < 16; ++c) s += gpb[(size_t)((n << 4) + c) * 5 + t];
      gram[n * 25 + sb * 5 + t] = s;
      gram[n * 25 + t * 5 + sb] = s;
    }
    __syncthreads();
    if (t == 0) {                                // bordered 6x6 solve, f32 GE w/ pivot
      int nact = kk_iter < 5 ? kk_iter : 5;
      float A[6][7];
      for (int i = 0; i < 5; ++i)
        for (int j = 0; j < 5; ++j)
          A[i + 1][j + 1] = (i < nact && j < nact)
              ? gram[n * 25 + i * 5 + j] + ((i == j) ? 1e-4f : 0.f)
              : ((i == j) ? 1.f : 0.f);
      A[0][0] = 0.f;
      for (int j = 0; j < 5; ++j) { float aj = (j < nact) ? 1.f : 0.f; A[0][j + 1] = aj; A[j + 1][0] = aj; }
      A[0][6] = 1.f;
      for (int i = 1; i < 6; ++i) A[i][6] = 0.f;
      for (int c = 0; c < 6; ++c) {
        int p = c; float mx = fabsf(A[c][c]);
        for (int r = c + 1; r < 6; ++r) { float v = fabsf(A[r][c]); if (v > mx) { mx = v; p = r; } }
        if (p != c) for (int q = c; q < 7; ++q) { float tmp = A[c][q]; A[c][q] = A[p][q]; A[p][q] = tmp; }
        float piv = A[c][c];
        for (int r = c + 1; r < 6; ++r) {
          float fмеждf = A[r][c] / piv;
          for (int q = c; q < 7; ++q) A[r][q] -= fмеждf * A[c][q];
        }
      }
      float sol[6];
      for (int r = 5; r >= 0; --r) {
        float s = A[r][6];
        for (int q = r + 1; q < 6; ++q) s -= A[r][q] * sol[q];
        sol[r] = s / A[r][r];
      }
      for (int j = 0; j < 5; ++j) alpha_s[j] = sol[j + 1];
    }
  } else {
    if (t < 5) alpha_s[t] = (t == 0) ? 1.f : 0.f;
  }
  __syncthreads();

  // body: xnew = sum_j alpha_j Fh_j ; zm = mask ? x : bf16(xnew)
  int lp = ((bid & 31) << 5) + (t >> 4);
  int p = (n << 10) + lp;
  int g = t & 15, px = p & 31;
  float a0 = alpha_s[0], a1 = alpha_s[1], a2 = alpha_s[2], a3 = alpha_s[3], a4 = alpha_s[4];
  size_t base = (size_t)p * 128 + ((size_t)g << 3);
  const float* f = Fh + base;
  f32x4 va = a0 * *(const f32x4*)(f)            + a1 * *(const f32x4*)(f + SLOT)
           + a2 * *(const f32x4*)(f + 2 * SLOT) + a3 * *(const f32x4*)(f + 3 * SLOT)
           + a4 * *(const f32x4*)(f + 4 * SLOT);
  f32x4 vb = a0 * *(const f32x4*)(f + 4)            + a1 * *(const f32x4*)(f + SLOT + 4)
           + a2 * *(const f32x4*)(f + 2 * SLOT + 4) + a3 * *(const f32x4*)(f + 3 * SLOT + 4)
           + a4 * *(const f32x4*)(f + 4 * SLOT + 4);
  *(f32x4*)(xnew + base) = va;
  *(f32x4*)(xnew + base + 4) = vb;
  int mk = mask_[p];
  size_t zoff = (size_t)p * 128 + (size_t)((g ^ (px & 7)) << 3);
  if (mk) {
    *(short8*)(zm + zoff) = *(const short8*)(xsw + zoff);
  } else {
    short8 o;
#pragma unroll
    for (int u = 0; u < 4; ++u) o[u] = (short)f2bf(va[u]);
#pragma unroll
    for (int u = 0; u < 4; ++u) o[4 + u] = (short)f2bf(vb[u]);
    *(short8*)(zm + zoff) = o;
  }
}

// ---------------- final: Fh[last_slot] NHWC f32 -> d_out NCHW f32
__global__ void __launch_bounds__(256) k_out(const float* __restrict__ Fh,
    const Ctrl* __restrict__ ctrl, float* __restrict__ out)
{
  __shared__ float T[64][129];
  int slot = ctrl->last_slot;
  const float* src = Fh + (size_t)slot * SLOT;
  int bid = blockIdx.x;                          // 512 = 32 batches * 16 segments
  int nb = bid >> 4, seg = bid & 15;
  int pixbase = (nb << 10) + (seg << 6);
  for (int it = 0; it < 32; ++it) {
    int idx = it * 256 + threadIdx.x;
    int pix = idx >> 7, c = idx & 127;
    T[pix][c] = src[(size_t)(pixbase + pix) * 128 + c];
  }
  __syncthreads();
  for (int it = 0; it < 32; ++it) {
    int idx = it * 256 + threadIdx.x;
    int c = idx >> 6, pix = idx & 63;
    out[(size_t)((nb << 7) + c) * 1024 + (seg << 6) + pix] = T[pix][c];
  }
}

extern "C" void kernel_launch(void* const* d_in, const int* in_sizes, int n_in,
                              void* d_out, int out_size, void* d_ws, size_t ws_size,
                              hipStream_t stream) {
  const float* x    = (const float*)d_in[0];   // [32,128,32,32]
  const float* W    = (const float*)d_in[1];   // [128,128,3,3]
  const float* bias = (const float*)d_in[2];   // [128]
  const int*   mask = (const int*)d_in[3];     // [32,1,32,32]
  float* out = (float*)d_out;
  char* ws = (char*)d_ws;

  float* Fh   = (float*)(ws + 0);              // 5 * 16,777,216 B
  u16*   G    = (u16*)(ws + 83886080);         // 5 * 8,388,608 B (packed-linear)
  float* xnew = (float*)(ws + 125829120);      // 16,777,216 B
  u16*   zm   = (u16*)(ws + 142606336);        // 8,388,608 B (swizzled NHWC)
  u16*   xsw  = (u16*)(ws + 150994944);        // 8,388,608 B
  u16*   Wb   = (u16*)(ws + 159383552);        // 294,912 B
  float* gram = (float*)(ws + 159678464);      // 32*25*4
  float* gp0  = (float*)(ws + 159681664);      // 512*5*4
  float* gp1  = (float*)(ws + 159691904);
  float* gp   = (float*)(ws + 159702144);
  float* resp = (float*)(ws + 159712384);      // 512*2*4
  Ctrl*  ctrl = (Ctrl*)(ws + 159716480);

  k_init<<<1, 64, 0, stream>>>(gram, ctrl);
  hipMemsetAsync(G, 0, (size_t)5 * SLOT * 2, stream);
  k_prepw<<<576, 256, 0, stream>>>(W, Wb);
  k_prepx<<<2048, 256, 0, stream>>>(x, mask, xsw, zm);

  // F0 = f(z0), z0 = 1/128 uniform
  k_conv<<<512, 512, 0, stream>>>(zm, nullptr, 1.0f / 128.0f, Wb, bias,
        Fh, G, 0, gp0, resp, ctrl, 0);
  // xnew = F0 (alpha = e0), zm from F0
  k_fx<<<1024, 512, 0, stream>>>(Fh, xnew, zm, xsw, mask,
        nullptr, 0, nullptr, -1, nullptr, 0, 0, 1, 1, gram, ctrl);
  // F1 = f(F0)
  k_conv<<<512, 512, 0, stream>>>(zm, xnew, 0.f, Wb, bias,
        Fh + SLOT, G, 1, gp1, resp, ctrl, 0);

  for (int k = 2; k < 50; ++k) {
    int slot = k % 5;
    if (k == 2)
      k_fx<<<1024, 512, 0, stream>>>(Fh, xnew, zm, xsw, mask,
            gp0, 0, gp1, 1, resp, 0, 0, k, 0, gram, ctrl);
    else
      k_fx<<<1024, 512, 0, stream>>>(Fh, xnew, zm, xsw, mask,
            gp, (k - 1) % 5, nullptr, -1, resp, 1, (k - 1) % 5, k, 0, gram, ctrl);
    k_conv<<<512, 512, 0, stream>>>(zm, xnew, 0.f, Wb, bias,
          Fh + (size_t)slot * SLOT, G, slot, gp, resp, ctrl, 1);
  }
  k_out<<<512, 256, 0, stream>>>(Fh, ctrl, out);
  (void)in_sizes; (void)n_in; (void)out_size; (void)ws_size;
}